// Round 5
// baseline (266.432 us; speedup 1.0000x reference)
//
#include <hip/hip_runtime.h>
#include <stdint.h>

#define IN_DIM  32768
#define OUT_DIM 32768
#define BATCH   1024
#define NT      1024
#define GRID    256                   // 1 block per CU, exact fill
#define RPB     4                     // rows per block
#define LDS_BYTES (2 * IN_DIM * 2)    // double-buffered fp16 row (2 x 64 KiB)

typedef float    fvec4 __attribute__((ext_vector_type(4)));
typedef uint32_t u32x4 __attribute__((ext_vector_type(4)));
typedef __fp16   h2v   __attribute__((ext_vector_type(2)));

__device__ __forceinline__ uint32_t pack2_f16(float lo, float hi) {
    h2v h = __builtin_amdgcn_cvt_pkrtz(lo, hi);   // lo->elem0(low16), hi->elem1
    return __builtin_bit_cast(uint32_t, h);
}
__device__ __forceinline__ float ldrow(const uint16_t* row, uint32_t byteoff) {
    __fp16 h = *(const __fp16*)((const char*)row + byteoff);
    return (float)h;
}
__device__ __forceinline__ float sel(uint32_t flag, float v) {
    return flag ? 1.0f - v : v;
}

// packed layout: low16 = (idx_a<<1) | flagA ; high16 = (idx_b<<1) | flagB
__global__ void pack_meta(const int* __restrict__ idx_a,
                          const int* __restrict__ idx_b,
                          const float* __restrict__ logits,
                          uint32_t* __restrict__ packed) {
    int j = blockIdx.x * blockDim.x + threadIdx.x;
    if (j >= OUT_DIM) return;
    uint32_t ia = (((uint32_t)idx_a[j]) << 1) & 0xFFFFu;
    uint32_t ib = (((uint32_t)idx_b[j]) << 1) & 0xFFFFu;
    if (logits[2 * j + 0] > 0.0f) ia |= 1u;   // sigmoid(l)>0.5 <=> l>0
    if (logits[2 * j + 1] > 0.0f) ib |= 1u;
    packed[j] = ia | (ib << 16);
}

// ---- asm helpers: loads that CANNOT be sunk or spilled -------------------
#define GLOAD(dst, ptr) \
    asm volatile("global_load_dwordx4 %0, %1, off" : "=v"(dst) : "v"(ptr) : "memory")

// vmcnt(8): the 8 prefetch loads are the oldest outstanding vmem ops; the 8
// newest are this row's nontemporal stores (vmcnt retires in issue order, so
// "<=8 outstanding" == "everything but the 8 newest stores is done").
// "+v" ties force every pf consumer to be scheduled after this wait.
#define WAIT_PF() \
    asm volatile("s_waitcnt vmcnt(8)" \
        : "+v"(pf0), "+v"(pf1), "+v"(pf2), "+v"(pf3), \
          "+v"(pf4), "+v"(pf5), "+v"(pf6), "+v"(pf7) :: "memory")

// barrier that does NOT drain vmcnt: LDS ordering only; output stores and
// next-row prefetch loads stay in flight across the row boundary.
#define LDS_BARRIER() \
    asm volatile("s_waitcnt lgkmcnt(0)\ns_barrier" ::: "memory")

// Persistent 1-block/CU, 4 rows, double-buffered LDS, asm-forced pipeline:
//   prefetch(k+1) issued a full compute-phase early; stores cross barriers.
__global__ __launch_bounds__(NT, 4) void logic_gather(
        const float* __restrict__ x,
        const uint32_t* __restrict__ packed,
        float* __restrict__ out) {
    extern __shared__ __align__(16) uint16_t lds[];   // [2][IN_DIM] fp16
    uint16_t* const buf0 = lds;
    uint16_t* const buf1 = lds + IN_DIM;
    const int t = threadIdx.x;
    const int b = blockIdx.x;

    // ---- meta: 8 asm loads -> guaranteed register residency for all 4 rows
    const char* mp = (const char*)packed + (size_t)t * 16;
    u32x4 p0, p1, p2, p3, p4, p5, p6, p7;
    GLOAD(p0, mp);              GLOAD(p1, mp + 1 * NT * 16);
    GLOAD(p2, mp + 2 * NT * 16); GLOAD(p3, mp + 3 * NT * 16);
    GLOAD(p4, mp + 4 * NT * 16); GLOAD(p5, mp + 5 * NT * 16);
    GLOAD(p6, mp + 6 * NT * 16); GLOAD(p7, mp + 7 * NT * 16);

    // ---- stage row 0 into buf0 (regular code; compiler inserts its own waits,
    //      which can only over-wait given the asm loads -> safe)
    {
        const float4* __restrict__ xr = (const float4*)(x + (size_t)b * IN_DIM);
        uint2* __restrict__ w64 = (uint2*)buf0;
#pragma unroll
        for (int s = 0; s < 8; ++s) {
            float4 v = xr[s * NT + t];
            uint2 h;
            h.x = pack2_f16(v.x, v.y);
            h.y = pack2_f16(v.z, v.w);
            w64[s * NT + t] = h;
        }
    }
    // meta guaranteed resident before first gather
    asm volatile("s_waitcnt vmcnt(0)"
        : "+v"(p0), "+v"(p1), "+v"(p2), "+v"(p3),
          "+v"(p4), "+v"(p5), "+v"(p6), "+v"(p7) :: "memory");

    // ---- issue prefetch of row 1 BEFORE the barrier (crosses it in flight)
    fvec4 pf0, pf1, pf2, pf3, pf4, pf5, pf6, pf7;
#define PREFETCH_ROW(krow) do {                                                   \
        const char* ap = (const char*)(x + (size_t)(b + (krow) * GRID) * IN_DIM)  \
                         + (size_t)t * 16;                                        \
        GLOAD(pf0, ap);               GLOAD(pf1, ap + 1 * NT * 16);               \
        GLOAD(pf2, ap + 2 * NT * 16); GLOAD(pf3, ap + 3 * NT * 16);               \
        GLOAD(pf4, ap + 4 * NT * 16); GLOAD(pf5, ap + 5 * NT * 16);               \
        GLOAD(pf6, ap + 6 * NT * 16); GLOAD(pf7, ap + 7 * NT * 16);               \
    } while (0)

    PREFETCH_ROW(1);
    LDS_BARRIER();

#define GITER(cur, o, i, P) do {                                                    \
        const uint32_t w0 = (P).x, w1 = (P).y, w2 = (P).z, w3 = (P).w;              \
        float va0 = ldrow(cur, w0 & 0xFFFEu), vb0 = ldrow(cur, (w0 >> 16) & 0xFFFEu); \
        float va1 = ldrow(cur, w1 & 0xFFFEu), vb1 = ldrow(cur, (w1 >> 16) & 0xFFFEu); \
        float va2 = ldrow(cur, w2 & 0xFFFEu), vb2 = ldrow(cur, (w2 >> 16) & 0xFFFEu); \
        float va3 = ldrow(cur, w3 & 0xFFFEu), vb3 = ldrow(cur, (w3 >> 16) & 0xFFFEu); \
        fvec4 res;                                                                  \
        res.x = sel(w0 & 1u, va0) * sel(w0 & 0x10000u, vb0);                        \
        res.y = sel(w1 & 1u, va1) * sel(w1 & 0x10000u, vb1);                        \
        res.z = sel(w2 & 1u, va2) * sel(w2 & 0x10000u, vb2);                        \
        res.w = sel(w3 & 1u, va3) * sel(w3 & 0x10000u, vb3);                        \
        __builtin_nontemporal_store(res, &(o)[(i) * NT + t]);                       \
    } while (0)

#define COMPUTE_ROW(cur, krow) do {                                                 \
        fvec4* __restrict__ o = (fvec4*)(out + (size_t)(b + (krow) * GRID) * OUT_DIM); \
        GITER(cur, o, 0, p0); GITER(cur, o, 1, p1);                                 \
        GITER(cur, o, 2, p2); GITER(cur, o, 3, p3);                                 \
        GITER(cur, o, 4, p4); GITER(cur, o, 5, p5);                                 \
        GITER(cur, o, 6, p6); GITER(cur, o, 7, p7);                                 \
    } while (0)

    // convert prefetched row to fp16 and write into nxt (pf consumed post-WAIT)
#define STAGE_PF(nxt) do {                                                          \
        uint2* __restrict__ w64 = (uint2*)(nxt);                                    \
        uint2 h;                                                                    \
        h.x = pack2_f16(pf0.x, pf0.y); h.y = pack2_f16(pf0.z, pf0.w); w64[0 * NT + t] = h; \
        h.x = pack2_f16(pf1.x, pf1.y); h.y = pack2_f16(pf1.z, pf1.w); w64[1 * NT + t] = h; \
        h.x = pack2_f16(pf2.x, pf2.y); h.y = pack2_f16(pf2.z, pf2.w); w64[2 * NT + t] = h; \
        h.x = pack2_f16(pf3.x, pf3.y); h.y = pack2_f16(pf3.z, pf3.w); w64[3 * NT + t] = h; \
        h.x = pack2_f16(pf4.x, pf4.y); h.y = pack2_f16(pf4.z, pf4.w); w64[4 * NT + t] = h; \
        h.x = pack2_f16(pf5.x, pf5.y); h.y = pack2_f16(pf5.z, pf5.w); w64[5 * NT + t] = h; \
        h.x = pack2_f16(pf6.x, pf6.y); h.y = pack2_f16(pf6.z, pf6.w); w64[6 * NT + t] = h; \
        h.x = pack2_f16(pf7.x, pf7.y); h.y = pack2_f16(pf7.z, pf7.w); w64[7 * NT + t] = h; \
    } while (0)

    // ---- row 0: compute from buf0; land row1 -> buf1; launch prefetch row2
    COMPUTE_ROW(buf0, 0);
    WAIT_PF();
    STAGE_PF(buf1);
    PREFETCH_ROW(2);          // in flight across barrier + row1 compute
    LDS_BARRIER();

    // ---- row 1
    COMPUTE_ROW(buf1, 1);
    WAIT_PF();
    STAGE_PF(buf0);
    PREFETCH_ROW(3);
    LDS_BARRIER();

    // ---- row 2
    COMPUTE_ROW(buf0, 2);
    WAIT_PF();
    STAGE_PF(buf1);
    LDS_BARRIER();

    // ---- row 3 (no prefetch; stores flushed at endpgm)
    COMPUTE_ROW(buf1, 3);

#undef PREFETCH_ROW
#undef GITER
#undef COMPUTE_ROW
#undef STAGE_PF
}

extern "C" void kernel_launch(void* const* d_in, const int* in_sizes, int n_in,
                              void* d_out, int out_size, void* d_ws, size_t ws_size,
                              hipStream_t stream) {
    const float* x      = (const float*)d_in[0];
    const float* logits = (const float*)d_in[1];
    const int*   idx_a  = (const int*)d_in[2];
    const int*   idx_b  = (const int*)d_in[3];
    uint32_t*    packed = (uint32_t*)d_ws;   // 128 KiB scratch
    float*       out    = (float*)d_out;

    static bool lds_opt_in = false;
    if (!lds_opt_in) {
        (void)hipFuncSetAttribute(reinterpret_cast<const void*>(logic_gather),
                                  hipFuncAttributeMaxDynamicSharedMemorySize, LDS_BYTES);
        lds_opt_in = true;
    }

    hipLaunchKernelGGL(pack_meta, dim3(OUT_DIM / 256), dim3(256), 0, stream,
                       idx_a, idx_b, logits, packed);
    hipLaunchKernelGGL(logic_gather, dim3(GRID), dim3(NT), LDS_BYTES, stream,
                       x, packed, out);
}